// Round 5
// baseline (580.706 us; speedup 1.0000x reference)
//
#include <hip/hip_runtime.h>
#include <math.h>

#define BB 4
#define HH 16
#define SS 1024
#define DD 64
#define QT 16     // q rows per block (one wave)
#define PTL 264   // padded p_tile row length (ushorts)

typedef __attribute__((ext_vector_type(8))) short bf16x8;
typedef __attribute__((ext_vector_type(4))) float f32x4;
typedef __attribute__((ext_vector_type(4))) int   i32x4;

static __device__ inline unsigned short f2bf(float f) {
    unsigned int u = __float_as_uint(f);
    u += 0x7fff + ((u >> 16) & 1);   // RNE
    return (unsigned short)(u >> 16);
}

// ---- pre-pass: fp32 -> bf16 for Q and K (row-major unchanged) ----
__global__ __launch_bounds__(256) void convert_qk(const float* __restrict__ q,
                                                  const float* __restrict__ k,
                                                  unsigned short* __restrict__ qb,
                                                  unsigned short* __restrict__ kb) {
    const int idx = blockIdx.x * 256 + threadIdx.x;     // 1,048,576 float4s
    float4 qv = ((const float4*)q)[idx];
    float4 kv = ((const float4*)k)[idx];
    ushort4 qo = make_ushort4(f2bf(qv.x), f2bf(qv.y), f2bf(qv.z), f2bf(qv.w));
    ushort4 ko = make_ushort4(f2bf(kv.x), f2bf(kv.y), f2bf(kv.z), f2bf(kv.w));
    ((ushort4*)qb)[idx] = qo;
    ((ushort4*)kb)[idx] = ko;
}

// ---- pre-pass: V [bh][k][d] fp32 -> Vt [bh][d][k] bf16, LDS-tiled ----
__global__ __launch_bounds__(256) void transpose_v(const float* __restrict__ v,
                                                   unsigned short* __restrict__ vt) {
    __shared__ unsigned short t[DD][258];
    const int bh = blockIdx.y;
    const int k0 = blockIdx.x * 256;
    const float* vb = v + ((size_t)bh * SS + k0) * DD;
#pragma unroll
    for (int j = 0; j < 16; ++j) {
        const int f   = j * 256 + threadIdx.x;
        const int row = f >> 4;
        const int d4  = (f & 15) << 2;
        float4 x = ((const float4*)vb)[f];
        t[d4 + 0][row] = f2bf(x.x);
        t[d4 + 1][row] = f2bf(x.y);
        t[d4 + 2][row] = f2bf(x.z);
        t[d4 + 3][row] = f2bf(x.w);
    }
    __syncthreads();
    unsigned short* vo = vt + (size_t)bh * DD * SS + k0;
#pragma unroll
    for (int j = 0; j < 8; ++j) {
        const int f  = j * 256 + threadIdx.x;
        const int d  = f >> 5;
        const int k8 = (f & 31) << 3;
        const unsigned int* lp = (const unsigned int*)&t[d][k8];
        uint4 w;
        w.x = lp[0]; w.y = lp[1]; w.z = lp[2]; w.w = lp[3];
        *(uint4*)(vo + (size_t)d * SS + k8) = w;
    }
}

// ---- main: ONE WAVE per block = (b, h, 16-q-row tile), all 1024 k. ----
// Zero barriers. Two-pass: pass1 streams QK^T with online (m,l); pass2
// recomputes scores (MFMA pipe is ~idle), normalizes, stores attn, and
// PV-accumulates per 256-k chunk through a wave-private LDS tile.
// S^T layout throughout (A=K, B=Q): lane(col,quad) holds 4 consecutive k
// of q-row col -> all global/LDS accesses are 8-16B wide.
__global__ __launch_bounds__(64) void attn_1wave(
    const unsigned short* __restrict__ qb,   // [BH][S][D] bf16
    const unsigned short* __restrict__ kb,   // [BH][S][D] bf16
    const unsigned short* __restrict__ vtb,  // [BH][D][S] bf16
    const float* __restrict__ add_attn,      // [B][S][S]
    const int*   __restrict__ mask,          // [B][S]
    float* __restrict__ out,                 // [BH][S][D]
    float* __restrict__ attn_out)            // [BH][S][S]
{
    // XCD-chunked mapping: HW round-robins blockIdx across 8 XCDs, so give
    // block P the logical id (P%8)*512 + P/8 -> each XCD gets a contiguous
    // 512-block range (32 qt-tiles x 16 heads, one b): bias/K/Vt stay L2-hot.
    const int P       = blockIdx.x;                  // 0..4095
    const int logical = ((P & 7) << 9) | (P >> 3);
    const int h  = logical & 15;
    const int g  = logical >> 4;        // 0..255
    const int qt = g & 63;
    const int b  = g >> 6;
    const int bh = b * HH + h;

    const int lane = threadIdx.x;       // 0..63
    const int col  = lane & 15;         // q index within tile
    const int quad = lane >> 4;         // k sub-chunk

    __shared__ unsigned short p_tile[QT][PTL];   // 8448 B, wave-private

    const int q0 = qt * QT;

    // Q fragment (B operand): Q[q0+col][quad*8+j (+32)]
    const unsigned short* qrow = qb + ((size_t)bh * SS + q0 + col) * DD + quad * 8;
    const bf16x8 bq0 = *(const bf16x8*)(qrow);
    const bf16x8 bq1 = *(const bf16x8*)(qrow + 32);

    const unsigned short* kbb = kb + (size_t)bh * SS * DD;
    const float* brow = add_attn + ((size_t)b * SS + q0 + col) * SS;
    const int*   mrow = mask + b * SS;

    // ---- pass 1: stream all 64 k-tiles, online (m,l) per lane ----
    float m = -3.0e38f, l = 0.0f;
#pragma unroll 4
    for (int t = 0; t < 64; ++t) {
        const unsigned short* kr = kbb + (size_t)(t * 16 + col) * DD + quad * 8;
        bf16x8 ak0 = *(const bf16x8*)(kr);
        bf16x8 ak1 = *(const bf16x8*)(kr + 32);
        f32x4 acc = {0.f, 0.f, 0.f, 0.f};
        acc = __builtin_amdgcn_mfma_f32_16x16x32_bf16(ak0, bq0, acc, 0, 0, 0);
        acc = __builtin_amdgcn_mfma_f32_16x16x32_bf16(ak1, bq1, acc, 0, 0, 0);
        const int kof = t * 16 + quad * 4;
        const f32x4 bv = *(const f32x4*)(brow + kof);
        const i32x4 mv = *(const i32x4*)(mrow + kof);
        const float s0 = mv[0] ? acc[0] * 0.125f + bv[0] : -1e9f;
        const float s1 = mv[1] ? acc[1] * 0.125f + bv[1] : -1e9f;
        const float s2 = mv[2] ? acc[2] * 0.125f + bv[2] : -1e9f;
        const float s3 = mv[3] ? acc[3] * 0.125f + bv[3] : -1e9f;
        const float tm = fmaxf(fmaxf(s0, s1), fmaxf(s2, s3));
        const float nm = fmaxf(m, tm);
        l = l * __expf(m - nm) + __expf(s0 - nm) + __expf(s1 - nm)
                               + __expf(s2 - nm) + __expf(s3 - nm);
        m = nm;
    }
    // cross-quad combine (lanes col, col+16, col+32, col+48): 2 shuffles
    {
        float om = __shfl_xor(m, 16), ol = __shfl_xor(l, 16);
        float nm = fmaxf(m, om);
        l = l * __expf(m - nm) + ol * __expf(om - nm);
        m = nm;
        om = __shfl_xor(m, 32); ol = __shfl_xor(l, 32);
        nm = fmaxf(m, om);
        l = l * __expf(m - nm) + ol * __expf(om - nm);
        m = nm;
    }
    const float inv = 1.0f / l;

    // ---- pass 2: recompute, normalize, store attn, PV per 256-k chunk ----
    const unsigned short* vt = vtb + (size_t)bh * DD * SS;
    float* arow = attn_out + ((size_t)bh * SS + q0 + col) * SS;
    f32x4 oacc[4];
#pragma unroll
    for (int dc = 0; dc < 4; ++dc) oacc[dc] = (f32x4){0.f, 0.f, 0.f, 0.f};

    for (int ck = 0; ck < 4; ++ck) {
        const int k0 = ck * 256;
#pragma unroll
        for (int tt = 0; tt < 16; ++tt) {
            const int t = ck * 16 + tt;
            const unsigned short* kr = kbb + (size_t)(t * 16 + col) * DD + quad * 8;
            bf16x8 ak0 = *(const bf16x8*)(kr);
            bf16x8 ak1 = *(const bf16x8*)(kr + 32);
            f32x4 acc = {0.f, 0.f, 0.f, 0.f};
            acc = __builtin_amdgcn_mfma_f32_16x16x32_bf16(ak0, bq0, acc, 0, 0, 0);
            acc = __builtin_amdgcn_mfma_f32_16x16x32_bf16(ak1, bq1, acc, 0, 0, 0);
            const int kof = t * 16 + quad * 4;
            const f32x4 bv = *(const f32x4*)(brow + kof);
            const i32x4 mv = *(const i32x4*)(mrow + kof);
            f32x4 pv;
            ushort4 pk;
#pragma unroll
            for (int r = 0; r < 4; ++r) {
                const float s = mv[r] ? acc[r] * 0.125f + bv[r] : -1e9f;
                const float p = __expf(s - m) * inv;
                pv[r] = p;
                ((unsigned short*)&pk)[r] = f2bf(p);
            }
            *(f32x4*)(arow + kof) = pv;                       // global, 16B
            *(ushort4*)&p_tile[col][tt * 16 + quad * 4] = pk; // LDS, 8B
        }
        // same-wave LDS write->read ordering (no barrier needed, 1 wave)
        asm volatile("s_waitcnt lgkmcnt(0)" ::: "memory");
#pragma unroll
        for (int c = 0; c < 8; ++c) {
            bf16x8 ap = *(const bf16x8*)&p_tile[col][c * 32 + quad * 8];
#pragma unroll
            for (int dc = 0; dc < 4; ++dc) {
                const unsigned short* vr =
                    vt + (size_t)(dc * 16 + col) * SS + k0 + c * 32 + quad * 8;
                bf16x8 av = *(const bf16x8*)(vr);
                oacc[dc] = __builtin_amdgcn_mfma_f32_16x16x32_bf16(av, ap, oacc[dc], 0, 0, 0);
            }
        }
        // WAR (next chunk's ds_write vs this chunk's ds_read) is safe: LDS ops
        // from one wave execute in order; MFMA uses are lgkm-fenced by compiler.
    }

    // ---- out: O[q=col][d=dc*16+quad*4+r], float4 stores ----
#pragma unroll
    for (int dc = 0; dc < 4; ++dc)
        *(f32x4*)(out + ((size_t)bh * SS + q0 + col) * DD + dc * 16 + quad * 4) = oacc[dc];
}

extern "C" void kernel_launch(void* const* d_in, const int* in_sizes, int n_in,
                              void* d_out, int out_size, void* d_ws, size_t ws_size,
                              hipStream_t stream) {
    const float* q        = (const float*)d_in[0];
    const float* k        = (const float*)d_in[1];
    const float* v        = (const float*)d_in[2];
    const float* add_attn = (const float*)d_in[3];
    const int*   mask     = (const int*)d_in[4];

    float* out      = (float*)d_out;
    float* attn_out = (float*)d_out + (size_t)BB * HH * SS * DD;

    const size_t nelem = (size_t)BB * HH * SS * DD;     // 4,194,304
    unsigned short* qb  = (unsigned short*)d_ws;
    unsigned short* kbb = qb + nelem;
    unsigned short* vtb = kbb + nelem;

    convert_qk<<<dim3(nelem / 4 / 256), dim3(256), 0, stream>>>(q, k, qb, kbb);
    transpose_v<<<dim3(SS / 256, BB * HH), dim3(256), 0, stream>>>(v, vtb);

    attn_1wave<<<dim3(BB * HH * (SS / QT)), dim3(64), 0, stream>>>(
        qb, kbb, vtb, add_attn, mask, out, attn_out);
}

// Round 6
// 451.697 us; speedup vs baseline: 1.2856x; 1.2856x over previous
//
#include <hip/hip_runtime.h>
#include <math.h>

#define BB 4
#define HH 16
#define SS 1024
#define DD 64
#define QT 16     // q rows per block
#define NKW 4     // waves per block, each owns KPW k-columns
#define KPW 256
#define HPB 4     // heads per block (bias reused from registers)
#define PTL 264   // padded p_tile row length (ushorts)
#define OSTR 68   // padded row stride (floats) for o-scratch overlay

typedef __attribute__((ext_vector_type(8))) short bf16x8;
typedef __attribute__((ext_vector_type(4))) float f32x4;
typedef __attribute__((ext_vector_type(4))) int   i32x4;

static __device__ inline unsigned short f2bf(float f) {
    unsigned int u = __float_as_uint(f);
    u += 0x7fff + ((u >> 16) & 1);   // RNE
    return (unsigned short)(u >> 16);
}

// ---- pre-pass: fp32 -> bf16 for Q and K (row-major unchanged) ----
__global__ __launch_bounds__(256) void convert_qk(const float* __restrict__ q,
                                                  const float* __restrict__ k,
                                                  unsigned short* __restrict__ qb,
                                                  unsigned short* __restrict__ kb) {
    const int idx = blockIdx.x * 256 + threadIdx.x;     // 1,048,576 float4s
    float4 qv = ((const float4*)q)[idx];
    float4 kv = ((const float4*)k)[idx];
    ushort4 qo = make_ushort4(f2bf(qv.x), f2bf(qv.y), f2bf(qv.z), f2bf(qv.w));
    ushort4 ko = make_ushort4(f2bf(kv.x), f2bf(kv.y), f2bf(kv.z), f2bf(kv.w));
    ((ushort4*)qb)[idx] = qo;
    ((ushort4*)kb)[idx] = ko;
}

// ---- pre-pass: V [bh][k][d] fp32 -> Vt [bh][d][k] bf16, LDS-tiled ----
__global__ __launch_bounds__(256) void transpose_v(const float* __restrict__ v,
                                                   unsigned short* __restrict__ vt) {
    __shared__ unsigned short t[DD][258];
    const int bh = blockIdx.y;
    const int k0 = blockIdx.x * 256;
    const float* vb = v + ((size_t)bh * SS + k0) * DD;
#pragma unroll
    for (int j = 0; j < 16; ++j) {
        const int f   = j * 256 + threadIdx.x;
        const int row = f >> 4;
        const int d4  = (f & 15) << 2;
        float4 x = ((const float4*)vb)[f];
        t[d4 + 0][row] = f2bf(x.x);
        t[d4 + 1][row] = f2bf(x.y);
        t[d4 + 2][row] = f2bf(x.z);
        t[d4 + 3][row] = f2bf(x.w);
    }
    __syncthreads();
    unsigned short* vo = vt + (size_t)bh * DD * SS + k0;
#pragma unroll
    for (int j = 0; j < 8; ++j) {
        const int f  = j * 256 + threadIdx.x;
        const int d  = f >> 5;
        const int k8 = (f & 31) << 3;
        const unsigned int* lp = (const unsigned int*)&t[d][k8];
        uint4 w;
        w.x = lp[0]; w.y = lp[1]; w.z = lp[2]; w.w = lp[3];
        *(uint4*)(vo + (size_t)d * SS + k8) = w;
    }
}

// ---- main: r4 structure + CONTIGUOUS attn stores via LDS row-staging ----
// S^T score layout (A=K, B=Q). The one change vs r4: instead of each lane
// storing its own f32x4 (16 scattered 64B half-line segments per wave-instr,
// 4KB row stride), fp32 P is staged through a 4KB/wave LDS buffer in 4
// row-groups and emitted as 64-lane x 16B CONTIGUOUS stores (1KB run, 8 full
// 128B lines per instr) -- the same pattern the 6.2 TB/s fill kernel uses.
__global__ __launch_bounds__(256, 2) void attn_mfma(
    const unsigned short* __restrict__ qb,   // [BH][S][D] bf16
    const unsigned short* __restrict__ kb,   // [BH][S][D] bf16
    const unsigned short* __restrict__ vtb,  // [BH][D][S] bf16
    const float* __restrict__ add_attn,      // [B][S][S]
    const int*   __restrict__ mask,          // [B][S]
    float* __restrict__ out,                 // [BH][S][D]
    float* __restrict__ attn_out)            // [BH][S][S]
{
    // bijective swizzle: hg-siblings of a (b,qt) bias tile land on one XCD
    const int P    = blockIdx.x;          // 0..1023
    const int xcd  = P & 7;
    const int slot = P >> 3;              // 0..127
    const int hg   = slot & 3;            // head group 0..3
    const int g    = ((slot >> 2) << 3) | xcd;   // 0..255
    const int qt   = g & 63;
    const int b    = g >> 6;

    const int tid  = threadIdx.x;
    const int wave = tid >> 6;
    const int lane = tid & 63;
    const int col  = lane & 15;      // q index within tile
    const int quad = lane >> 4;      // k sub-chunk (quad*4 + r)

    __shared__ unsigned short p_tile[NKW][QT][PTL];   // 33,792 B
    __shared__ float a_stage[NKW][4][264];            // 16,896 B (4 rows/group)
    __shared__ float red_m[NKW][QT];
    __shared__ float red_l[NKW][QT];
    // wave-local O scratch overlaid on this wave's p_tile region
    float* o_w = (float*)&p_tile[wave][0][0];

    const int q0  = qt * QT;
    const int wk0 = wave * KPW;

    // ---- bias tile once, float4 loads, mask folded; lives across heads ----
    const float* brow = add_attn + ((size_t)b * SS + q0 + col) * SS;
    const int*   mrow = mask + b * SS;
    float br[16][4];
#pragma unroll
    for (int t = 0; t < 16; ++t) {
        const int kof = wk0 + t * 16 + quad * 4;
        const f32x4 bv = *(const f32x4*)(brow + kof);
        const i32x4 mv = *(const i32x4*)(mrow + kof);
#pragma unroll
        for (int r = 0; r < 4; ++r)
            br[t][r] = mv[r] ? bv[r] : -1e9f;
    }

    for (int hi = 0; hi < HPB; ++hi) {
        const int bh = b * HH + hg * HPB + hi;

        // Q fragment (B operand): Q[q0+col][quad*8+j (+32)]
        const unsigned short* qrow = qb + ((size_t)bh * SS + q0 + col) * DD + quad * 8;
        const bf16x8 bq0 = *(const bf16x8*)(qrow);
        const bf16x8 bq1 = *(const bf16x8*)(qrow + 32);

        const unsigned short* kbb = kb + (size_t)bh * SS * DD;

        // ---- QK^T (swapped): s[t][r] = S[k=wk0+t*16+quad*4+r][q=col] ----
        float s[16][4];
#pragma unroll
        for (int t = 0; t < 16; ++t) {
            const unsigned short* kr = kbb + (size_t)(wk0 + t * 16 + col) * DD + quad * 8;
            bf16x8 ak0 = *(const bf16x8*)(kr);
            bf16x8 ak1 = *(const bf16x8*)(kr + 32);
            f32x4 acc = {0.f, 0.f, 0.f, 0.f};
            acc = __builtin_amdgcn_mfma_f32_16x16x32_bf16(ak0, bq0, acc, 0, 0, 0);
            acc = __builtin_amdgcn_mfma_f32_16x16x32_bf16(ak1, bq1, acc, 0, 0, 0);
#pragma unroll
            for (int r = 0; r < 4; ++r)
                s[t][r] = acc[r] * 0.125f + br[t][r];   // masked: ~-1e9 -> exp 0
        }

        // ---- in-wave row max over this wave's 256 k (scalar per lane) ----
        float m = s[0][0];
#pragma unroll
        for (int t = 0; t < 16; ++t)
#pragma unroll
            for (int r = 0; r < 4; ++r) m = fmaxf(m, s[t][r]);
        m = fmaxf(m, __shfl_xor(m, 16));
        m = fmaxf(m, __shfl_xor(m, 32));

        // ---- exp + in-wave sum ----
        float l = 0.f;
#pragma unroll
        for (int t = 0; t < 16; ++t)
#pragma unroll
            for (int r = 0; r < 4; ++r) {
                float e = __expf(s[t][r] - m);
                s[t][r] = e;
                l += e;
            }
        l += __shfl_xor(l, 16);
        l += __shfl_xor(l, 32);

        if (quad == 0) { red_m[wave][col] = m; red_l[wave][col] = l; }
        __syncthreads();

        // ---- cross-wave combine (rescale per-wave sums) ----
        const float m0 = red_m[0][col], m1 = red_m[1][col];
        const float m2 = red_m[2][col], m3 = red_m[3][col];
        const float gm = fmaxf(fmaxf(m0, m1), fmaxf(m2, m3));
        const float L  = red_l[0][col] * __expf(m0 - gm) +
                         red_l[1][col] * __expf(m1 - gm) +
                         red_l[2][col] * __expf(m2 - gm) +
                         red_l[3][col] * __expf(m3 - gm);
        const float sc = __expf(m - gm) / L;

        // ---- normalize in place; p_tile (bf16) for PV ----
#pragma unroll
        for (int t = 0; t < 16; ++t) {
            ushort4 pk;
#pragma unroll
            for (int r = 0; r < 4; ++r) {
                const float p = s[t][r] * sc;
                s[t][r] = p;
                ((unsigned short*)&pk)[r] = f2bf(p);
            }
            *(ushort4*)&p_tile[wave][col][t * 16 + quad * 4] = pk;
        }

        // ---- attn stores: stage 4 rows at a time, emit 1KB-contiguous ----
        float* arow0 = attn_out + ((size_t)bh * SS + q0) * SS + wk0;
#pragma unroll
        for (int gg = 0; gg < 4; ++gg) {
            if ((col >> 2) == gg) {
                const int rr = col & 3;
#pragma unroll
                for (int t = 0; t < 16; ++t) {
                    f32x4 d;
                    d[0] = s[t][0]; d[1] = s[t][1]; d[2] = s[t][2]; d[3] = s[t][3];
                    *(f32x4*)&a_stage[wave][rr][t * 16 + quad * 4] = d;
                }
            }
            asm volatile("s_waitcnt lgkmcnt(0)" ::: "memory");
#pragma unroll
            for (int rr = 0; rr < 4; ++rr) {
                f32x4 d = *(const f32x4*)&a_stage[wave][rr][lane * 4];
                *(f32x4*)(arow0 + (size_t)(gg * 4 + rr) * SS + lane * 4) = d;
            }
            // same-wave LDS is in-order; next group's writes cannot pass these reads
        }

        // ---- PV (swapped): A=Vt (d->row), B=P (q->col) ----
        const unsigned short* vt = vtb + (size_t)bh * DD * SS;
        f32x4 oacc[4];
#pragma unroll
        for (int dc = 0; dc < 4; ++dc) oacc[dc] = (f32x4){0.f, 0.f, 0.f, 0.f};
#pragma unroll
        for (int c = 0; c < 8; ++c) {
            bf16x8 ap = *(const bf16x8*)(&p_tile[wave][col][c * 32 + quad * 8]);
#pragma unroll
            for (int dc = 0; dc < 4; ++dc) {
                const unsigned short* vr =
                    vt + (size_t)(dc * 16 + col) * SS + wk0 + c * 32 + quad * 8;
                bf16x8 av = *(const bf16x8*)(vr);
                oacc[dc] = __builtin_amdgcn_mfma_f32_16x16x32_bf16(av, ap, oacc[dc], 0, 0, 0);
            }
        }
        // partial O into overlay (after all P reads of this wave's region)
#pragma unroll
        for (int dc = 0; dc < 4; ++dc)
            *(f32x4*)(o_w + col * OSTR + dc * 16 + quad * 4) = oacc[dc];
        __syncthreads();

        // ---- cross-wave sum: one float4 per thread, float4 out store ----
        {
            const int qr = tid >> 4;           // 0..15
            const int d0 = (tid & 15) << 2;    // 0..60
            const float* ob = (const float*)&p_tile[0][0][0];
            const int ws = QT * PTL / 2;       // floats per wave p_tile region
            f32x4 a0 = *(const f32x4*)(ob + 0 * ws + qr * OSTR + d0);
            f32x4 a1 = *(const f32x4*)(ob + 1 * ws + qr * OSTR + d0);
            f32x4 a2 = *(const f32x4*)(ob + 2 * ws + qr * OSTR + d0);
            f32x4 a3 = *(const f32x4*)(ob + 3 * ws + qr * OSTR + d0);
            f32x4 o4 = a0 + a1 + a2 + a3;
            *(f32x4*)(out + ((size_t)bh * SS + q0 + qr) * DD + d0) = o4;
        }
        __syncthreads();   // protect p_tile/red before next head reuses them
    }
}

extern "C" void kernel_launch(void* const* d_in, const int* in_sizes, int n_in,
                              void* d_out, int out_size, void* d_ws, size_t ws_size,
                              hipStream_t stream) {
    const float* q        = (const float*)d_in[0];
    const float* k        = (const float*)d_in[1];
    const float* v        = (const float*)d_in[2];
    const float* add_attn = (const float*)d_in[3];
    const int*   mask     = (const int*)d_in[4];

    float* out      = (float*)d_out;
    float* attn_out = (float*)d_out + (size_t)BB * HH * SS * DD;

    const size_t nelem = (size_t)BB * HH * SS * DD;     // 4,194,304
    unsigned short* qb  = (unsigned short*)d_ws;
    unsigned short* kbb = qb + nelem;
    unsigned short* vtb = kbb + nelem;

    convert_qk<<<dim3(nelem / 4 / 256), dim3(256), 0, stream>>>(q, k, qb, kbb);
    transpose_v<<<dim3(SS / 256, BB * HH), dim3(256), 0, stream>>>(v, vtb);

    attn_mfma<<<dim3(SS / QT * (HH / HPB) * BB), dim3(256), 0, stream>>>(
        qb, kbb, vtb, add_attn, mask, out, attn_out);
}

// Round 7
// 451.613 us; speedup vs baseline: 1.2858x; 1.0002x over previous
//
#include <hip/hip_runtime.h>
#include <math.h>

#define BB 4
#define HH 16
#define SS 1024
#define DD 64
#define QT 16     // q rows per block
#define NKW 4     // waves per block, each owns KPW k-columns
#define KPW 256
#define HPB 4     // heads per block (bias reused from registers)
#define PTL 264   // padded p_tile row length (ushorts); wave region = 2112 floats
#define OSTR 66   // padded row stride (floats) for o-scratch overlay

typedef __attribute__((ext_vector_type(8))) short bf16x8;
typedef __attribute__((ext_vector_type(4))) float f32x4;
typedef __attribute__((ext_vector_type(4))) int   i32x4;

static __device__ inline unsigned short f2bf(float f) {
    unsigned int u = __float_as_uint(f);
    u += 0x7fff + ((u >> 16) & 1);   // RNE
    return (unsigned short)(u >> 16);
}

// Barrier WITHOUT the vmcnt(0) drain __syncthreads() would emit.
// Only LDS ordering is required across waves in this kernel; global stores
// (attn_out/out) are write-only and may stay in flight across barriers.
static __device__ __forceinline__ void bar_lgkm() {
    asm volatile("s_waitcnt lgkmcnt(0)" ::: "memory");
    __builtin_amdgcn_s_barrier();
}

// ---- pre-pass: fp32 -> bf16 for Q and K (row-major unchanged) ----
__global__ __launch_bounds__(256) void convert_qk(const float* __restrict__ q,
                                                  const float* __restrict__ k,
                                                  unsigned short* __restrict__ qb,
                                                  unsigned short* __restrict__ kb) {
    const int idx = blockIdx.x * 256 + threadIdx.x;     // 1,048,576 float4s
    float4 qv = ((const float4*)q)[idx];
    float4 kv = ((const float4*)k)[idx];
    ushort4 qo = make_ushort4(f2bf(qv.x), f2bf(qv.y), f2bf(qv.z), f2bf(qv.w));
    ushort4 ko = make_ushort4(f2bf(kv.x), f2bf(kv.y), f2bf(kv.z), f2bf(kv.w));
    ((ushort4*)qb)[idx] = qo;
    ((ushort4*)kb)[idx] = ko;
}

// ---- pre-pass: V [bh][k][d] fp32 -> Vt [bh][d][k] bf16, LDS-tiled ----
__global__ __launch_bounds__(256) void transpose_v(const float* __restrict__ v,
                                                   unsigned short* __restrict__ vt) {
    __shared__ unsigned short t[DD][258];
    const int bh = blockIdx.y;
    const int k0 = blockIdx.x * 256;
    const float* vb = v + ((size_t)bh * SS + k0) * DD;
#pragma unroll
    for (int j = 0; j < 16; ++j) {
        const int f   = j * 256 + threadIdx.x;
        const int row = f >> 4;
        const int d4  = (f & 15) << 2;
        float4 x = ((const float4*)vb)[f];
        t[d4 + 0][row] = f2bf(x.x);
        t[d4 + 1][row] = f2bf(x.y);
        t[d4 + 2][row] = f2bf(x.z);
        t[d4 + 3][row] = f2bf(x.w);
    }
    __syncthreads();
    unsigned short* vo = vt + (size_t)bh * DD * SS + k0;
#pragma unroll
    for (int j = 0; j < 8; ++j) {
        const int f  = j * 256 + threadIdx.x;
        const int d  = f >> 5;
        const int k8 = (f & 31) << 3;
        const unsigned int* lp = (const unsigned int*)&t[d][k8];
        uint4 w;
        w.x = lp[0]; w.y = lp[1]; w.z = lp[2]; w.w = lp[3];
        *(uint4*)(vo + (size_t)d * SS + k8) = w;
    }
}

// ---- main: r6 structure, but (a) lgkm-only barriers (no store drains),
//      (b) LDS back to 34.3KB (4 blocks/CU) by overlaying BOTH the attn
//      staging buffer and the O scratch onto the dead p_tile region
//      (PV runs before attn emission). ----
__global__ __launch_bounds__(256, 2) void attn_mfma(
    const unsigned short* __restrict__ qb,   // [BH][S][D] bf16
    const unsigned short* __restrict__ kb,   // [BH][S][D] bf16
    const unsigned short* __restrict__ vtb,  // [BH][D][S] bf16
    const float* __restrict__ add_attn,      // [B][S][S]
    const int*   __restrict__ mask,          // [B][S]
    float* __restrict__ out,                 // [BH][S][D]
    float* __restrict__ attn_out)            // [BH][S][S]
{
    // bijective swizzle: hg-siblings of a (b,qt) bias tile land on one XCD
    const int P    = blockIdx.x;          // 0..1023
    const int xcd  = P & 7;
    const int slot = P >> 3;              // 0..127
    const int hg   = slot & 3;            // head group 0..3
    const int g    = ((slot >> 2) << 3) | xcd;   // 0..255
    const int qt   = g & 63;
    const int b    = g >> 6;

    const int tid  = threadIdx.x;
    const int wave = tid >> 6;
    const int lane = tid & 63;
    const int col  = lane & 15;      // q index within tile
    const int quad = lane >> 4;      // k sub-chunk (quad*4 + r)

    __shared__ unsigned short p_tile[NKW][QT][PTL];   // 33,792 B total
    __shared__ float red_m[NKW][QT];
    __shared__ float red_l[NKW][QT];
    // Overlays on this wave's p_tile region (2112 floats), valid AFTER PV:
    //   [0    .. 1056): a_stage, 4 rows x 264 floats (attn staging)
    //   [1056 .. 2112): o_w, 16 rows x OSTR floats (partial O)
    float* wbase = (float*)&p_tile[wave][0][0];
    float* o_w   = wbase + 1056;

    const int q0  = qt * QT;
    const int wk0 = wave * KPW;

    // ---- bias tile once, float4 loads, mask folded; lives across heads ----
    const float* brow = add_attn + ((size_t)b * SS + q0 + col) * SS;
    const int*   mrow = mask + b * SS;
    float br[16][4];
#pragma unroll
    for (int t = 0; t < 16; ++t) {
        const int kof = wk0 + t * 16 + quad * 4;
        const f32x4 bv = *(const f32x4*)(brow + kof);
        const i32x4 mv = *(const i32x4*)(mrow + kof);
#pragma unroll
        for (int r = 0; r < 4; ++r)
            br[t][r] = mv[r] ? bv[r] : -1e9f;
    }

    for (int hi = 0; hi < HPB; ++hi) {
        const int bh = b * HH + hg * HPB + hi;

        // Q fragment (B operand): Q[q0+col][quad*8+j (+32)]
        const unsigned short* qrow = qb + ((size_t)bh * SS + q0 + col) * DD + quad * 8;
        const bf16x8 bq0 = *(const bf16x8*)(qrow);
        const bf16x8 bq1 = *(const bf16x8*)(qrow + 32);

        const unsigned short* kbb = kb + (size_t)bh * SS * DD;

        // ---- QK^T (swapped): s[t][r] = S[k=wk0+t*16+quad*4+r][q=col] ----
        float s[16][4];
#pragma unroll
        for (int t = 0; t < 16; ++t) {
            const unsigned short* kr = kbb + (size_t)(wk0 + t * 16 + col) * DD + quad * 8;
            bf16x8 ak0 = *(const bf16x8*)(kr);
            bf16x8 ak1 = *(const bf16x8*)(kr + 32);
            f32x4 acc = {0.f, 0.f, 0.f, 0.f};
            acc = __builtin_amdgcn_mfma_f32_16x16x32_bf16(ak0, bq0, acc, 0, 0, 0);
            acc = __builtin_amdgcn_mfma_f32_16x16x32_bf16(ak1, bq1, acc, 0, 0, 0);
#pragma unroll
            for (int r = 0; r < 4; ++r)
                s[t][r] = acc[r] * 0.125f + br[t][r];   // masked: ~-1e9 -> exp 0
        }

        // ---- in-wave max / exp / sum (scalar per lane, 2 shuffles each) ----
        float m = s[0][0];
#pragma unroll
        for (int t = 0; t < 16; ++t)
#pragma unroll
            for (int r = 0; r < 4; ++r) m = fmaxf(m, s[t][r]);
        m = fmaxf(m, __shfl_xor(m, 16));
        m = fmaxf(m, __shfl_xor(m, 32));

        float l = 0.f;
#pragma unroll
        for (int t = 0; t < 16; ++t)
#pragma unroll
            for (int r = 0; r < 4; ++r) {
                float e = __expf(s[t][r] - m);
                s[t][r] = e;
                l += e;
            }
        l += __shfl_xor(l, 16);
        l += __shfl_xor(l, 32);

        if (quad == 0) { red_m[wave][col] = m; red_l[wave][col] = l; }
        bar_lgkm();                                   // BAR1 (lgkm only)

        const float m0 = red_m[0][col], m1 = red_m[1][col];
        const float m2 = red_m[2][col], m3 = red_m[3][col];
        const float gm = fmaxf(fmaxf(m0, m1), fmaxf(m2, m3));
        const float L  = red_l[0][col] * __expf(m0 - gm) +
                         red_l[1][col] * __expf(m1 - gm) +
                         red_l[2][col] * __expf(m2 - gm) +
                         red_l[3][col] * __expf(m3 - gm);
        const float sc = __expf(m - gm) / L;

        // ---- normalize in place; p_tile (bf16) for PV ----
#pragma unroll
        for (int t = 0; t < 16; ++t) {
            ushort4 pk;
#pragma unroll
            for (int r = 0; r < 4; ++r) {
                const float p = s[t][r] * sc;
                s[t][r] = p;
                ((unsigned short*)&pk)[r] = f2bf(p);
            }
            *(ushort4*)&p_tile[wave][col][t * 16 + quad * 4] = pk;
        }
        asm volatile("s_waitcnt lgkmcnt(0)" ::: "memory");  // p writes -> PV reads

        // ---- PV (swapped): A=Vt (d->row), B=P (q->col) ----
        const unsigned short* vt = vtb + (size_t)bh * DD * SS;
        f32x4 oacc[4];
#pragma unroll
        for (int dc = 0; dc < 4; ++dc) oacc[dc] = (f32x4){0.f, 0.f, 0.f, 0.f};
#pragma unroll
        for (int c = 0; c < 8; ++c) {
            bf16x8 ap = *(const bf16x8*)(&p_tile[wave][col][c * 32 + quad * 8]);
#pragma unroll
            for (int dc = 0; dc < 4; ++dc) {
                const unsigned short* vr =
                    vt + (size_t)(dc * 16 + col) * SS + wk0 + c * 32 + quad * 8;
                bf16x8 av = *(const bf16x8*)(vr);
                oacc[dc] = __builtin_amdgcn_mfma_f32_16x16x32_bf16(av, ap, oacc[dc], 0, 0, 0);
            }
        }
        asm volatile("s_waitcnt lgkmcnt(0)" ::: "memory");  // PV p-reads done
        // p_tile region for this wave is now dead -> overlays become valid.

        // partial O into overlay [1056..2112)
#pragma unroll
        for (int dc = 0; dc < 4; ++dc)
            *(f32x4*)(o_w + col * OSTR + dc * 16 + quad * 4) = oacc[dc];

        // ---- attn emission: stage 4 rows at a time in overlay [0..1056),
        //      store 64-lane x 16B contiguous (1KB run, full lines) ----
        {
            float* arow0 = attn_out + ((size_t)bh * SS + q0) * SS + wk0;
            float (*a_st)[264] = (float(*)[264])wbase;
#pragma unroll
            for (int gg = 0; gg < 4; ++gg) {
                if ((col >> 2) == gg) {
                    const int rr = col & 3;
#pragma unroll
                    for (int t = 0; t < 16; ++t) {
                        f32x4 d;
                        d[0] = s[t][0]; d[1] = s[t][1];
                        d[2] = s[t][2]; d[3] = s[t][3];
                        *(f32x4*)&a_st[rr][t * 16 + quad * 4] = d;
                    }
                }
                asm volatile("s_waitcnt lgkmcnt(0)" ::: "memory");
#pragma unroll
                for (int rr = 0; rr < 4; ++rr) {
                    f32x4 d = *(const f32x4*)&a_st[rr][lane * 4];
                    *(f32x4*)(arow0 + (size_t)(gg * 4 + rr) * SS + lane * 4) = d;
                }
                // same-wave LDS in-order: next group's writes can't pass these reads
            }
        }
        bar_lgkm();                                   // BAR2: o_w visible to all

        // ---- cross-wave sum: one float4 per thread, float4 out store ----
        {
            const int qr = tid >> 4;           // 0..15
            const int d0 = (tid & 15) << 2;    // 0..60
            const float* ob = (const float*)&p_tile[0][0][0];
            const int ws = QT * PTL / 2;       // 2112 floats per wave region
            f32x4 a0 = *(const f32x4*)(ob + 0 * ws + 1056 + qr * OSTR + d0);
            f32x4 a1 = *(const f32x4*)(ob + 1 * ws + 1056 + qr * OSTR + d0);
            f32x4 a2 = *(const f32x4*)(ob + 2 * ws + 1056 + qr * OSTR + d0);
            f32x4 a3 = *(const f32x4*)(ob + 3 * ws + 1056 + qr * OSTR + d0);
            f32x4 o4 = a0 + a1 + a2 + a3;
            *(f32x4*)(out + ((size_t)bh * SS + q0 + qr) * DD + d0) = o4;
        }
        bar_lgkm();                                   // BAR3: o_w reads done
    }
}

extern "C" void kernel_launch(void* const* d_in, const int* in_sizes, int n_in,
                              void* d_out, int out_size, void* d_ws, size_t ws_size,
                              hipStream_t stream) {
    const float* q        = (const float*)d_in[0];
    const float* k        = (const float*)d_in[1];
    const float* v        = (const float*)d_in[2];
    const float* add_attn = (const float*)d_in[3];
    const int*   mask     = (const int*)d_in[4];

    float* out      = (float*)d_out;
    float* attn_out = (float*)d_out + (size_t)BB * HH * SS * DD;

    const size_t nelem = (size_t)BB * HH * SS * DD;     // 4,194,304
    unsigned short* qb  = (unsigned short*)d_ws;
    unsigned short* kbb = qb + nelem;
    unsigned short* vtb = kbb + nelem;

    convert_qk<<<dim3(nelem / 4 / 256), dim3(256), 0, stream>>>(q, k, qb, kbb);
    transpose_v<<<dim3(SS / 256, BB * HH), dim3(256), 0, stream>>>(v, vtb);

    attn_mfma<<<dim3(SS / QT * (HH / HPB) * BB), dim3(256), 0, stream>>>(
        qb, kbb, vtb, add_attn, mask, out, attn_out);
}